// Round 12
// baseline (7538.706 us; speedup 1.0000x reference)
//
#include <hip/hip_runtime.h>

#define T_STEPS 365
#define BATCH   2048
#define INP     9
#define HID     50
#define MB      16          // batch per block (MFMA col dim)
#define NBLK    (BATCH/MB)  // 128
#define NT      320         // 5 waves: 0-3 compute 3 tiles each, 4 = tile12+util
#define NTILES  13
#define L2E     1.4426950408889634f

typedef __attribute__((ext_vector_type(8))) short short8;
typedef __attribute__((ext_vector_type(4))) float float4v;

__device__ __forceinline__ unsigned f2bf(float v) {
    unsigned u = __builtin_bit_cast(unsigned, v);
    return (u + 0x7FFFu + ((u >> 16) & 1u)) >> 16;
}

// lgkm-only phase barrier: LDS drains, global loads/stores stay in flight.
#define PHASE_BARRIER() do {                                  \
    asm volatile("s_waitcnt lgkmcnt(0)" ::: "memory");        \
    __builtin_amdgcn_s_barrier();                             \
    __builtin_amdgcn_sched_barrier(0);                        \
} while (0)

// Transposed LDS: HX[p][(k>>3)*128 + m*8 + (k&7)] (ushort units).
// K layout: 0-49 h0 | 50-58 x | 59-63 zero | 64-113 h1 | 114-127 zero.
// A wave's b128 fragment read is a CONTIGUOUS 1 KB block -> conflict-free.
__device__ __forceinline__ int tx_off(int m, int k) {
    return ((k >> 3) * 128) + m * 8 + (k & 7);
}

// 7-trans LSTM cell: 5 exp2 + 2 rcp. Single-rcp c-update via triple product:
//   c' = [c*(1+Ei)(1+Eg) + (1-Eg)(1+Ef)] * rcp((1+Ef)(1+Ei)(1+Eg))
// Inputs exp2-prescaled (-L2E i,f,o; -2L2E g); clamped |a|<=40 so the
// triple product stays < 2^121 (no overflow).
__device__ __forceinline__ float cell7_(float a0, float a1, float a2, float a3,
                                        float& c) {
    a0 = fminf(fmaxf(a0, -40.f), 40.f);
    a1 = fminf(fmaxf(a1, -40.f), 40.f);
    a2 = fminf(fmaxf(a2, -40.f), 40.f);
    a3 = fminf(fmaxf(a3, -40.f), 40.f);
    const float Ei = __builtin_amdgcn_exp2f(a0);
    const float Ef = __builtin_amdgcn_exp2f(a1);
    const float Eg = __builtin_amdgcn_exp2f(a2);
    const float Eo = __builtin_amdgcn_exp2f(a3);
    const float pi = 1.f + Ei, pf = 1.f + Ef, pg = 1.f + Eg, po = 1.f + Eo;
    const float pig = pi * pg;
    const float R = __builtin_amdgcn_rcpf(pf * pig);
    c = (c * pig + (1.f - Eg) * pf) * R;
    const float Ec = __builtin_amdgcn_exp2f(c * (-2.f * L2E));
    const float pc = 1.f + Ec;
    return (1.f - Ec) * __builtin_amdgcn_rcpf(po * pc);
}

// 5-wave merged-role LSTM: ~1 wave/SIMD (no intra-SIMD lockstep), 20 b128
// read burst (vs 32), 6 independent cell chains per wave. Waves 0-3 own
// tiles {w,w+4,w+8}; wave 4 owns tile 12 + x staging + FC spare-row store.
__global__ __launch_bounds__(NT, 1)
void lstm_w5(const float* __restrict__ x,
             const float* __restrict__ w_ih0, const float* __restrict__ w_hh0,
             const float* __restrict__ b_ih0, const float* __restrict__ b_hh0,
             const float* __restrict__ w_ih1, const float* __restrict__ w_hh1,
             const float* __restrict__ b_ih1, const float* __restrict__ b_hh1,
             const float* __restrict__ fc_w, const float* __restrict__ fc_b,
             float* __restrict__ out)
{
    __shared__ __align__(16) unsigned short HX[2][2048];   // 8 KB

    const int tid  = threadIdx.x;
    const int w    = tid >> 6;
    const int lid  = tid & 63;
    const int mcol = lid & 15;
    const int kgrp = lid >> 4;
    const int kb8  = kgrp * 8;
    const int b0   = blockIdx.x * MB;
    const bool w4  = (w == 4);
    const int  ntt = w4 ? 1 : 3;             // tiles this wave owns

    // ---- per-tile weights (gate-interleaved rows: r = 4*unit + gate ->
    //      original row = gate*50 + unit) ----
    short8 wk0[3][2], wk1[3][2], wk2[3][2];
    float  bs0[3][4], bs1[3][4];
    float  cst0[3] = {0.f, 0.f, 0.f}, cst1[3] = {0.f, 0.f, 0.f};

    for (int tt = 0; tt < ntt; ++tt) {
        const int T  = w4 ? 12 : (w + 4 * tt);
        const int r  = T * 16 + mcol;
        const bool rv = (r < 4 * HID);
        const int u_r = r >> 2, g_r = r & 3;
        const int orig = g_r * HID + u_r;
        const float rsc = (g_r == 2) ? (-2.f * L2E) : (-L2E);
        const bool fcrow = (T == 12) && (mcol == 8);   // spare row 200
        #pragma unroll
        for (int q = 0; q < 2; ++q) {
            short8 a{}, b{}, c{};
            #pragma unroll
            for (int j = 0; j < 8; ++j) {
                const int k = q * 32 + kb8 + j;
                float v0 = 0.f, v1 = 0.f, v2 = 0.f;
                if (rv) {
                    if (k < HID) {
                        v0 = w_hh0[orig * HID + k] * rsc;
                        v1 = w_ih1[orig * HID + k] * rsc;
                        v2 = w_hh1[orig * HID + k] * rsc;
                    } else if (k < HID + INP) {
                        v0 = w_ih0[orig * INP + (k - HID)] * rsc;
                    }
                }
                if (fcrow) v2 = (k < HID) ? fc_w[k] : 0.f;   // unscaled FC row
                a[j] = (short)f2bf(v0);
                b[j] = (short)f2bf(v1);
                c[j] = (short)f2bf(v2);
            }
            wk0[tt][q] = a; wk1[tt][q] = b; wk2[tt][q] = c;
        }
        #pragma unroll
        for (int rr = 0; rr < 4; ++rr) {
            const int row = T * 16 + kgrp * 4 + rr;   // = 4*u + gate(rr)
            const bool bv = (row < 4 * HID);
            const int uu = row >> 2;
            const float bsc = (rr == 2) ? (-2.f * L2E) : (-L2E);
            bs0[tt][rr] = bv ? (b_ih0[rr * HID + uu] + b_hh0[rr * HID + uu]) * bsc : 0.f;
            bs1[tt][rr] = bv ? (b_ih1[rr * HID + uu] + b_hh1[rr * HID + uu]) * bsc : 0.f;
            if (row == 4 * HID) bs1[tt][rr] = fc_b[0];       // FC bias (row 200)
        }
    }

    // ---- x staging identity (wave 4, lanes 0-47, 3 values each) ----
    const bool xact = w4 && (lid < 48);
    float xr[3] = {0.f, 0.f, 0.f};

    // ---- LDS init ----
    for (int i = tid; i < 2 * 2048; i += NT) (&HX[0][0])[i] = 0;
    __syncthreads();
    if (xact) {
        #pragma unroll
        for (int q = 0; q < 3; ++q) {
            const int xi = lid * 3 + q;
            if (xi < MB * INP) {
                const int m = xi / INP, j = xi - m * INP;
                // x(0) into buf1 (phase 0 reads cur = 1); xr <- x(1)
                HX[1][tx_off(m, HID + j)] =
                    (unsigned short)f2bf(x[(size_t)(b0 + m) * INP + j]);
                xr[q] = x[((size_t)BATCH + b0 + m) * INP + j];
            }
        }
    }
    __syncthreads();

    for (int ph = 0; ph <= T_STEPS + 1; ++ph) {
        const int cur = (ph + 1) & 1, nxt = ph & 1;

        // x(ph+2) loads issued at phase top (land a full phase before use)
        float xn[3] = {0.f, 0.f, 0.f};
        if (xact && ph + 2 < T_STEPS) {
            #pragma unroll
            for (int q = 0; q < 3; ++q) {
                const int xi = lid * 3 + q;
                if (xi < MB * INP) {
                    const int m = xi / INP, j = xi - m * INP;
                    xn[q] = x[((size_t)(ph + 2) * BATCH + b0 + m) * INP + j];
                }
            }
        }

        // shared fragments: contiguous-1KB b128 reads, conflict-free.
        const int base = mcol * 8;
        const short8 f0 = *(const short8*)&HX[cur][(kgrp)      * 128 + base];
        const short8 f1 = *(const short8*)&HX[cur][(4  + kgrp) * 128 + base];
        const short8 f2 = *(const short8*)&HX[cur][(8  + kgrp) * 128 + base];
        const short8 f3 = *(const short8*)&HX[cur][(12 + kgrp) * 128 + base];

        for (int tt = 0; tt < ntt; ++tt) {
            const int T = w4 ? 12 : (w + 4 * tt);
            const int u = T * 4 + kgrp;

            // ---- chain A: layer0 step ph ----
            if (ph < T_STEPS) {
                float4v acc = {bs0[tt][0], bs0[tt][1], bs0[tt][2], bs0[tt][3]};
                acc = __builtin_amdgcn_mfma_f32_16x16x32_bf16(wk0[tt][0], f0, acc, 0, 0, 0);
                acc = __builtin_amdgcn_mfma_f32_16x16x32_bf16(wk0[tt][1], f1, acc, 0, 0, 0);
                const float h0v = cell7_(acc[0], acc[1], acc[2], acc[3], cst0[tt]);
                if (u < HID) HX[nxt][tx_off(mcol, u)] = (unsigned short)f2bf(h0v);
            }
            // ---- chain B: layer1 step ph-1 (+ FC row) ----
            if (ph >= 1) {
                float4v accA = {bs1[tt][0], bs1[tt][1], bs1[tt][2], bs1[tt][3]};
                float4v accB = {0.f, 0.f, 0.f, 0.f};
                accA = __builtin_amdgcn_mfma_f32_16x16x32_bf16(wk1[tt][0], f0, accA, 0, 0, 0);
                accB = __builtin_amdgcn_mfma_f32_16x16x32_bf16(wk2[tt][0], f2, accB, 0, 0, 0);
                accA = __builtin_amdgcn_mfma_f32_16x16x32_bf16(wk1[tt][1], f1, accA, 0, 0, 0);
                accB = __builtin_amdgcn_mfma_f32_16x16x32_bf16(wk2[tt][1], f3, accB, 0, 0, 0);
                const float a0 = accA[0] + accB[0];
                const float a1 = accA[1] + accB[1];
                const float a2 = accA[2] + accB[2];
                const float a3 = accA[3] + accB[3];
                // FC output = row 200 (tile 12, kgrp 2, reg 0)
                if (T == 12 && kgrp == 2 && ph >= 2)
                    out[(size_t)(ph - 2) * BATCH + b0 + mcol] = a0;
                if (ph <= T_STEPS) {
                    const float h1v = cell7_(a0, a1, a2, a3, cst1[tt]);
                    if (u < HID) HX[nxt][tx_off(mcol, 64 + u)] = (unsigned short)f2bf(h1v);
                }
            }
        }

        // ---- x staging: write x(ph+1) (loaded a phase ago) ----
        if (xact && ph + 1 < T_STEPS) {
            #pragma unroll
            for (int q = 0; q < 3; ++q) {
                const int xi = lid * 3 + q;
                if (xi < MB * INP) {
                    const int m = xi / INP, j = xi - m * INP;
                    HX[nxt][tx_off(m, HID + j)] = (unsigned short)f2bf(xr[q]);
                }
            }
        }
        if (xact) {
            #pragma unroll
            for (int q = 0; q < 3; ++q) xr[q] = xn[q];
        }
        PHASE_BARRIER();
    }
}

extern "C" void kernel_launch(void* const* d_in, const int* in_sizes, int n_in,
                              void* d_out, int out_size, void* d_ws, size_t ws_size,
                              hipStream_t stream) {
    const float* x     = (const float*)d_in[0];
    const float* w_ih0 = (const float*)d_in[1];
    const float* w_hh0 = (const float*)d_in[2];
    const float* b_ih0 = (const float*)d_in[3];
    const float* b_hh0 = (const float*)d_in[4];
    const float* w_ih1 = (const float*)d_in[5];
    const float* w_hh1 = (const float*)d_in[6];
    const float* b_ih1 = (const float*)d_in[7];
    const float* b_hh1 = (const float*)d_in[8];
    const float* fc_w  = (const float*)d_in[9];
    const float* fc_b  = (const float*)d_in[10];
    float* out = (float*)d_out;

    lstm_w5<<<dim3(NBLK), dim3(NT), 0, stream>>>(
        x, w_ih0, w_hh0, b_ih0, b_hh0,
        w_ih1, w_hh1, b_ih1, b_hh1, fc_w, fc_b, out);
}

// Round 13
// 352.541 us; speedup vs baseline: 21.3839x; 21.3839x over previous
//
#include <hip/hip_runtime.h>

#define T_STEPS 365
#define BATCH   2048
#define INP     9
#define HID     50
#define MB      16          // batch per block (MFMA col dim)
#define NBLK    (BATCH/MB)  // 128
#define NT      512         // 8 waves: 0-6 compute (tiles w, w+7), 7 util
#define NWC     7
#define NTILES  13          // 208 gate rows >= 200
#define L2E     1.4426950408889634f

typedef __attribute__((ext_vector_type(8))) short short8;
typedef __attribute__((ext_vector_type(4))) float float4v;

__device__ __forceinline__ unsigned f2bf(float v) {
    unsigned u = __builtin_bit_cast(unsigned, v);
    return (u + 0x7FFFu + ((u >> 16) & 1u)) >> 16;
}

// lgkm-only phase barrier: LDS drains, global loads/stores stay in flight.
#define PHASE_BARRIER() do {                                  \
    asm volatile("s_waitcnt lgkmcnt(0)" ::: "memory");        \
    __builtin_amdgcn_s_barrier();                             \
    __builtin_amdgcn_sched_barrier(0);                        \
} while (0)

// Transposed LDS: HX[p][(k>>3)*128 + m*8 + (k&7)] (ushort units).
// K layout: 0-49 h0 | 50-58 x | 59-63 zero | 64-113 h1 | 114-127 zero.
// A wave's b128 fragment read is a CONTIGUOUS 1 KB block -> conflict-free.
__device__ __forceinline__ int tx_off(int m, int k) {
    return ((k >> 3) * 128) + m * 8 + (k & 7);
}

// rcp-merged LSTM cell: 5 exp2 + 3 rcp. Inputs exp2-prescaled
// (-L2E for i,f,o; -2L2E for g).
__device__ __forceinline__ float cell_(float a0, float a1, float a2, float a3,
                                       float& c) {
    const float Ei = __builtin_amdgcn_exp2f(a0);
    const float Ef = __builtin_amdgcn_exp2f(a1);
    const float Eg = __builtin_amdgcn_exp2f(a2);
    const float Eo = __builtin_amdgcn_exp2f(a3);
    const float ig = (1.f - Eg) * __builtin_amdgcn_rcpf((1.f + Ei) * (1.f + Eg));
    c = __builtin_amdgcn_rcpf(1.f + Ef) * c + ig;
    const float Ec = __builtin_amdgcn_exp2f(c * (-2.f * L2E));
    return (1.f - Ec) * __builtin_amdgcn_rcpf((1.f + Eo) * (1.f + Ec));
}

// r10 skeleton with the per-wave body FLATTENED for chain parallelism:
// all 6 MFMA accumulator chains live simultaneously (launch_bounds(,1)
// lifts the VGPR cap to 256 so the compiler keeps them in registers),
// MFMAs issued round-robin, then 4 independent cell chains, then writes.
__global__ __launch_bounds__(NT, 1)
void lstm_ilp(const float* __restrict__ x,
              const float* __restrict__ w_ih0, const float* __restrict__ w_hh0,
              const float* __restrict__ b_ih0, const float* __restrict__ b_hh0,
              const float* __restrict__ w_ih1, const float* __restrict__ w_hh1,
              const float* __restrict__ b_ih1, const float* __restrict__ b_hh1,
              const float* __restrict__ fc_w, const float* __restrict__ fc_b,
              float* __restrict__ out)
{
    __shared__ __align__(16) unsigned short HX[2][2048];   // 8 KB

    const int tid  = threadIdx.x;
    const int w    = tid >> 6;
    const int lid  = tid & 63;
    const int mcol = lid & 15;
    const int kgrp = lid >> 4;
    const int kb8  = kgrp * 8;
    const int b0   = blockIdx.x * MB;
    const bool cw  = (w < NWC);
    const int t0   = cw ? w : 0;
    const int t1   = t0 + NWC;
    const bool t1v = cw && (t1 < NTILES);    // waves 0-5 have a second tile

    // ---- per-tile weights (gate-interleaved rows: r = 4*unit + gate ->
    //      original row = gate*50 + unit) ----
    short8 wk0[2][2], wk1[2][2], wk2[2][2];
    float  bs0[2][4], bs1[2][4];
    float  cst0[2] = {0.f, 0.f}, cst1[2] = {0.f, 0.f};

    #pragma unroll
    for (int tt = 0; tt < 2; ++tt) {
        const int T  = t0 + NWC * tt;
        const bool tv = cw && (T < NTILES);
        const int r  = T * 16 + mcol;
        const bool rv = tv && (r < 4 * HID);
        const int u_r = r >> 2, g_r = r & 3;
        const int orig = g_r * HID + u_r;
        const float rsc = (g_r == 2) ? (-2.f * L2E) : (-L2E);
        const bool fcrow = tv && (T == 12) && (mcol == 8);   // spare row 200
        #pragma unroll
        for (int q = 0; q < 2; ++q) {
            short8 a{}, b{}, c{};
            #pragma unroll
            for (int j = 0; j < 8; ++j) {
                const int k = q * 32 + kb8 + j;
                float v0 = 0.f, v1 = 0.f, v2 = 0.f;
                if (rv) {
                    if (k < HID) {
                        v0 = w_hh0[orig * HID + k] * rsc;
                        v1 = w_ih1[orig * HID + k] * rsc;
                        v2 = w_hh1[orig * HID + k] * rsc;
                    } else if (k < HID + INP) {
                        v0 = w_ih0[orig * INP + (k - HID)] * rsc;
                    }
                }
                if (fcrow) v2 = (k < HID) ? fc_w[k] : 0.f;   // unscaled FC row
                a[j] = (short)f2bf(v0);
                b[j] = (short)f2bf(v1);
                c[j] = (short)f2bf(v2);
            }
            wk0[tt][q] = a; wk1[tt][q] = b; wk2[tt][q] = c;
        }
        #pragma unroll
        for (int rr = 0; rr < 4; ++rr) {
            const int row = T * 16 + kgrp * 4 + rr;   // = 4*u + gate(rr)
            const bool bv = tv && (row < 4 * HID);
            const int uu = row >> 2;
            const float bsc = (rr == 2) ? (-2.f * L2E) : (-L2E);
            bs0[tt][rr] = bv ? (b_ih0[rr * HID + uu] + b_hh0[rr * HID + uu]) * bsc : 0.f;
            bs1[tt][rr] = bv ? (b_ih1[rr * HID + uu] + b_hh1[rr * HID + uu]) * bsc : 0.f;
            if (tv && row == 4 * HID) bs1[tt][rr] = fc_b[0];  // FC bias (row 200)
        }
    }

    // ---- util wave (w == 7): lanes 0-47 stage x (3 values each) ----
    const bool xact = (!cw) && (lid < 48);
    float xr[3] = {0.f, 0.f, 0.f};

    // ---- LDS init ----
    for (int i = tid; i < 2 * 2048; i += NT) (&HX[0][0])[i] = 0;
    __syncthreads();
    if (xact) {
        #pragma unroll
        for (int q = 0; q < 3; ++q) {
            const int xi = lid * 3 + q;
            if (xi < MB * INP) {
                const int m = xi / INP, j = xi - m * INP;
                // x(0) into buf1 (phase 0 reads cur = 1); xr <- x(1)
                HX[1][tx_off(m, HID + j)] =
                    (unsigned short)f2bf(x[(size_t)(b0 + m) * INP + j]);
                xr[q] = x[((size_t)BATCH + b0 + m) * INP + j];
            }
        }
    }
    __syncthreads();

    const int u0 = t0 * 4 + kgrp;            // <= 27, always a valid unit
    const int u1 = t1 * 4 + kgrp;            // mask with u1 < HID
    const bool fclane = t1v && (t1 == 12) && (kgrp == 2);

    for (int ph = 0; ph <= T_STEPS + 1; ++ph) {
        const int cur = (ph + 1) & 1, nxt = ph & 1;

        if (cw) {
            const int base = mcol * 8;
            const short8 f0 = *(const short8*)&HX[cur][(kgrp)      * 128 + base];
            const short8 f1 = *(const short8*)&HX[cur][(4  + kgrp) * 128 + base];
            const short8 f2 = *(const short8*)&HX[cur][(8  + kgrp) * 128 + base];
            const short8 f3 = *(const short8*)&HX[cur][(12 + kgrp) * 128 + base];

            // ---- flattened MFMA issue: 6 independent 2-deep chains ----
            float4v aA0 = {bs0[0][0], bs0[0][1], bs0[0][2], bs0[0][3]};
            float4v aP0 = {bs1[0][0], bs1[0][1], bs1[0][2], bs1[0][3]};
            float4v aQ0 = {0.f, 0.f, 0.f, 0.f};
            float4v aA1 = {bs0[1][0], bs0[1][1], bs0[1][2], bs0[1][3]};
            float4v aP1 = {bs1[1][0], bs1[1][1], bs1[1][2], bs1[1][3]};
            float4v aQ1 = {0.f, 0.f, 0.f, 0.f};
            aA0 = __builtin_amdgcn_mfma_f32_16x16x32_bf16(wk0[0][0], f0, aA0, 0, 0, 0);
            aP0 = __builtin_amdgcn_mfma_f32_16x16x32_bf16(wk1[0][0], f0, aP0, 0, 0, 0);
            aQ0 = __builtin_amdgcn_mfma_f32_16x16x32_bf16(wk2[0][0], f2, aQ0, 0, 0, 0);
            if (t1v) {
                aA1 = __builtin_amdgcn_mfma_f32_16x16x32_bf16(wk0[1][0], f0, aA1, 0, 0, 0);
                aP1 = __builtin_amdgcn_mfma_f32_16x16x32_bf16(wk1[1][0], f0, aP1, 0, 0, 0);
                aQ1 = __builtin_amdgcn_mfma_f32_16x16x32_bf16(wk2[1][0], f2, aQ1, 0, 0, 0);
            }
            aA0 = __builtin_amdgcn_mfma_f32_16x16x32_bf16(wk0[0][1], f1, aA0, 0, 0, 0);
            aP0 = __builtin_amdgcn_mfma_f32_16x16x32_bf16(wk1[0][1], f1, aP0, 0, 0, 0);
            aQ0 = __builtin_amdgcn_mfma_f32_16x16x32_bf16(wk2[0][1], f3, aQ0, 0, 0, 0);
            if (t1v) {
                aA1 = __builtin_amdgcn_mfma_f32_16x16x32_bf16(wk0[1][1], f1, aA1, 0, 0, 0);
                aP1 = __builtin_amdgcn_mfma_f32_16x16x32_bf16(wk1[1][1], f1, aP1, 0, 0, 0);
                aQ1 = __builtin_amdgcn_mfma_f32_16x16x32_bf16(wk2[1][1], f3, aQ1, 0, 0, 0);
            }

            // ---- 4 independent cell chains ----
            float h0v0 = 0.f, h0v1 = 0.f, h1v0 = 0.f, h1v1 = 0.f;
            if (ph < T_STEPS) {
                h0v0 = cell_(aA0[0], aA0[1], aA0[2], aA0[3], cst0[0]);
                if (t1v)
                    h0v1 = cell_(aA1[0], aA1[1], aA1[2], aA1[3], cst0[1]);
            }
            if (ph >= 1) {
                const float b00 = aP0[0] + aQ0[0], b01 = aP0[1] + aQ0[1];
                const float b02 = aP0[2] + aQ0[2], b03 = aP0[3] + aQ0[3];
                const float b10 = aP1[0] + aQ1[0], b11 = aP1[1] + aQ1[1];
                const float b12 = aP1[2] + aQ1[2], b13 = aP1[3] + aQ1[3];
                // FC output = spare row 200 (tile 12, kgrp 2, reg 0)
                if (fclane && ph >= 2)
                    out[(size_t)(ph - 2) * BATCH + b0 + mcol] = b10;
                if (ph <= T_STEPS) {
                    h1v0 = cell_(b00, b01, b02, b03, cst1[0]);
                    if (t1v)
                        h1v1 = cell_(b10, b11, b12, b13, cst1[1]);
                }
            }

            // ---- writes (after all chains) ----
            if (ph < T_STEPS) {
                HX[nxt][tx_off(mcol, u0)] = (unsigned short)f2bf(h0v0);
                if (t1v && u1 < HID)
                    HX[nxt][tx_off(mcol, u1)] = (unsigned short)f2bf(h0v1);
            }
            if (ph >= 1 && ph <= T_STEPS) {
                HX[nxt][tx_off(mcol, 64 + u0)] = (unsigned short)f2bf(h1v0);
                if (t1v && u1 < HID)
                    HX[nxt][tx_off(mcol, 64 + u1)] = (unsigned short)f2bf(h1v1);
            }
        } else if (xact) {
            // ---- x staging: write x(ph+1) (loaded a phase ago), load x(ph+2) ----
            #pragma unroll
            for (int q = 0; q < 3; ++q) {
                const int xi = lid * 3 + q;
                if (xi < MB * INP) {
                    const int m = xi / INP, j = xi - m * INP;
                    float xn = 0.f;
                    if (ph + 2 < T_STEPS)
                        xn = x[((size_t)(ph + 2) * BATCH + b0 + m) * INP + j];
                    if (ph + 1 < T_STEPS)
                        HX[nxt][tx_off(m, HID + j)] = (unsigned short)f2bf(xr[q]);
                    xr[q] = xn;
                }
            }
        }
        PHASE_BARRIER();
    }
}

extern "C" void kernel_launch(void* const* d_in, const int* in_sizes, int n_in,
                              void* d_out, int out_size, void* d_ws, size_t ws_size,
                              hipStream_t stream) {
    const float* x     = (const float*)d_in[0];
    const float* w_ih0 = (const float*)d_in[1];
    const float* w_hh0 = (const float*)d_in[2];
    const float* b_ih0 = (const float*)d_in[3];
    const float* b_hh0 = (const float*)d_in[4];
    const float* w_ih1 = (const float*)d_in[5];
    const float* w_hh1 = (const float*)d_in[6];
    const float* b_ih1 = (const float*)d_in[7];
    const float* b_hh1 = (const float*)d_in[8];
    const float* fc_w  = (const float*)d_in[9];
    const float* fc_b  = (const float*)d_in[10];
    float* out = (float*)d_out;

    lstm_ilp<<<dim3(NBLK), dim3(NT), 0, stream>>>(
        x, w_ih0, w_hh0, b_ih0, b_hh0,
        w_ih1, w_hh1, b_ih1, b_hh1, fc_w, fc_b, out);
}